// Round 1
// baseline (858.905 us; speedup 1.0000x reference)
//
#include <hip/hip_runtime.h>
#include <math.h>

#define N_NODES 100000
#define N_EDGES 1600000
#define EPRIME  (N_EDGES + N_NODES)
#define NEG_SLOPE 0.2f

// ---------------- edge dtype detect (int64 vs int32) ----------------
__global__ __launch_bounds__(256) void detect_k(const unsigned* __restrict__ w,
                                                unsigned* __restrict__ flag) {
    __shared__ int any;
    if (threadIdx.x == 0) any = 0;
    __syncthreads();
    int nz = 0;
    for (int i = threadIdx.x; i < 1024; i += 256)
        if (w[2 * i + 1] != 0u) nz = 1;
    if (nz) atomicOr(&any, 1);
    __syncthreads();
    if (threadIdx.x == 0) flag[0] = any ? 0u : 1u;  // 1 => int64
}

// ---------------- CSR build ----------------
__global__ __launch_bounds__(256) void init_k(int* __restrict__ counts,
                                              int* __restrict__ fill) {
    int n = blockIdx.x * blockDim.x + threadIdx.x;
    if (n < N_NODES) { counts[n] = 1; fill[n] = 0; }  // 1 = self loop
}

__global__ __launch_bounds__(256) void count_k(const int* __restrict__ ei,
                                               const unsigned* __restrict__ flag,
                                               int* __restrict__ counts) {
    int e = blockIdx.x * blockDim.x + threadIdx.x;
    if (e >= N_EDGES) return;
    int d = flag[0] ? ei[2 * (N_EDGES + e)] : ei[N_EDGES + e];
    atomicAdd(&counts[d], 1);
}

// exclusive scan of counts[0..N-1] -> rowptr[0..N], 1024 elems/block
__global__ __launch_bounds__(256) void scan1_k(const int* __restrict__ counts,
                                               int* __restrict__ rowptr,
                                               int* __restrict__ bsums) {
    __shared__ int s[256];
    int t = threadIdx.x;
    int base = blockIdx.x * 1024 + t * 4;
    int v[4];
#pragma unroll
    for (int j = 0; j < 4; ++j)
        v[j] = (base + j < N_NODES) ? counts[base + j] : 0;
    int tsum = v[0] + v[1] + v[2] + v[3];
    s[t] = tsum;
    __syncthreads();
    for (int off = 1; off < 256; off <<= 1) {
        int x = (t >= off) ? s[t - off] : 0;
        __syncthreads();
        s[t] += x;
        __syncthreads();
    }
    if (t == 255) bsums[blockIdx.x] = s[255];
    int run = s[t] - tsum;  // exclusive prefix for this thread (block-local)
#pragma unroll
    for (int j = 0; j < 4; ++j) {
        if (base + j <= N_NODES) rowptr[base + j] = run;
        run += v[j];
    }
}

__global__ void scan2_k(int* __restrict__ bsums, int nb) {
    if (threadIdx.x == 0 && blockIdx.x == 0) {
        int run = 0;
        for (int i = 0; i < nb; ++i) { int c = bsums[i]; bsums[i] = run; run += c; }
    }
}

__global__ __launch_bounds__(256) void scan3_k(int* __restrict__ rowptr,
                                               const int* __restrict__ bsums) {
    int t = threadIdx.x;
    int base = blockIdx.x * 1024 + t * 4;
    int add = bsums[blockIdx.x];
#pragma unroll
    for (int j = 0; j < 4; ++j)
        if (base + j <= N_NODES) rowptr[base + j] += add;
}

__global__ __launch_bounds__(256) void scatter_k(const int* __restrict__ ei,
                                                 const unsigned* __restrict__ flag,
                                                 const int* __restrict__ rowptr,
                                                 int* __restrict__ fill,
                                                 int* __restrict__ col) {
    int t = blockIdx.x * blockDim.x + threadIdx.x;
    if (t >= EPRIME) return;
    int s, d;
    if (t < N_EDGES) {
        if (flag[0]) { s = ei[2 * t]; d = ei[2 * (N_EDGES + t)]; }
        else         { s = ei[t];     d = ei[N_EDGES + t]; }
    } else {
        s = d = t - N_EDGES;
    }
    int pos = rowptr[d] + atomicAdd(&fill[d], 1);
    col[pos] = s;
}

// ---------------- GEMM1: h1 = x @ W1  (N x 512) @ (512 x 64) ----------------
__global__ __launch_bounds__(256) void gemm1_k(const float* __restrict__ x,
                                               const float* __restrict__ W1,
                                               float* __restrict__ h1) {
    __shared__ float xs[32 * 512];
    int t = threadIdx.x;
    int row0 = blockIdx.x * 32;
    // stage 32 rows x 512 floats = 4096 float4
    for (int i = t; i < 32 * 128; i += 256) {
        int r = i >> 7, q = i & 127;
        int gr = row0 + r;
        float4 v = make_float4(0.f, 0.f, 0.f, 0.f);
        if (gr < N_NODES) v = ((const float4*)x)[(size_t)gr * 128 + q];
        ((float4*)xs)[r * 128 + q] = v;
    }
    __syncthreads();
    int w = t >> 6, lane = t & 63;
    int r0 = w * 8;
    float acc[8] = {0.f, 0.f, 0.f, 0.f, 0.f, 0.f, 0.f, 0.f};
    for (int k = 0; k < 512; k += 4) {
        float w0 = W1[(k + 0) * 64 + lane];
        float w1 = W1[(k + 1) * 64 + lane];
        float w2 = W1[(k + 2) * 64 + lane];
        float w3 = W1[(k + 3) * 64 + lane];
#pragma unroll
        for (int r = 0; r < 8; ++r) {
            float4 xv = ((const float4*)xs)[(r0 + r) * 128 + (k >> 2)];
            acc[r] += xv.x * w0 + xv.y * w1 + xv.z * w2 + xv.w * w3;
        }
    }
#pragma unroll
    for (int r = 0; r < 8; ++r) {
        int gr = row0 + r0 + r;
        if (gr < N_NODES) h1[(size_t)gr * 64 + lane] = acc[r];
    }
}

// ---------------- attn1: one wave per node, lane = channel (64ch) ----------------
__global__ __launch_bounds__(256) void attn1_k(const float* __restrict__ h1,
                                               const int* __restrict__ rowptr,
                                               const int* __restrict__ col,
                                               const float* __restrict__ attl,
                                               const float* __restrict__ attr,
                                               const float* __restrict__ b1,
                                               float* __restrict__ hout) {
    int wid = (blockIdx.x * blockDim.x + threadIdx.x) >> 6;  // node
    int lane = threadIdx.x & 63;
    if (wid >= N_NODES) return;
    float xi = h1[(size_t)wid * 64 + lane];
    float al = attl[lane];
    float ar = attr[lane];
    float ard = xi * ar;
    ard += __shfl_xor(ard, 1); ard += __shfl_xor(ard, 2); ard += __shfl_xor(ard, 4);
    int beg = rowptr[wid], end = rowptr[wid + 1];

    float m = -INFINITY, lsum = 0.f, acc = 0.f;
    int e = beg;
    int s = col[e];
    float xj = h1[(size_t)s * 64 + lane];
    while (true) {
        float xjc = xj;
        int en = e + 1;
        if (en < end) {
            int s2 = col[en];
            xj = h1[(size_t)s2 * 64 + lane];
        }
        float dot = xi * xjc;
        float ald = xjc * al;
        dot += __shfl_xor(dot, 1); ald += __shfl_xor(ald, 1);
        dot += __shfl_xor(dot, 2); ald += __shfl_xor(ald, 2);
        dot += __shfl_xor(dot, 4); ald += __shfl_xor(ald, 4);
        float a = (ald + ard) * (1.f / (1.f + __expf(-dot)));
        a = a > 0.f ? a : NEG_SLOPE * a;
        float mn = fmaxf(m, a);
        float so = __expf(m - mn);
        float p = __expf(a - mn);
        lsum = lsum * so + p;
        acc = acc * so + p * xjc;
        m = mn;
        e = en;
        if (e >= end) break;
    }
    float o = acc / lsum + b1[lane];
    o = o > 0.f ? o : (__expf(o) - 1.f);  // ELU
    hout[(size_t)wid * 64 + lane] = o;
}

// ---------------- GEMM2: h2 = hout @ W2  (N x 64) @ (64 x 128) ----------------
__global__ __launch_bounds__(256) void gemm2_k(const float* __restrict__ h,
                                               const float* __restrict__ W2,
                                               float* __restrict__ h2) {
    __shared__ float xs[32 * 64];
    int t = threadIdx.x;
    int row0 = blockIdx.x * 32;
    for (int i = t; i < 32 * 16; i += 256) {
        int r = i >> 4, q = i & 15;
        int gr = row0 + r;
        float4 v = make_float4(0.f, 0.f, 0.f, 0.f);
        if (gr < N_NODES) v = ((const float4*)h)[(size_t)gr * 16 + q];
        ((float4*)xs)[r * 16 + q] = v;
    }
    __syncthreads();
    int w = t >> 6, lane = t & 63;
    int r0 = w * 8;
    float2 acc[8];
#pragma unroll
    for (int r = 0; r < 8; ++r) acc[r] = make_float2(0.f, 0.f);
    for (int k = 0; k < 64; ++k) {
        float2 wv = ((const float2*)W2)[k * 64 + lane];
#pragma unroll
        for (int r = 0; r < 8; ++r) {
            float xv = xs[(r0 + r) * 64 + k];
            acc[r].x += xv * wv.x;
            acc[r].y += xv * wv.y;
        }
    }
#pragma unroll
    for (int r = 0; r < 8; ++r) {
        int gr = row0 + r0 + r;
        if (gr < N_NODES) ((float2*)h2)[(size_t)gr * 64 + lane] = acc[r];
    }
}

// ---------------- attn2: one wave per node, 2 channels/lane (128ch) ----------------
// fused: online softmax agg + head mean + bias + log_softmax
__global__ __launch_bounds__(256) void attn2_k(const float* __restrict__ h2,
                                               const int* __restrict__ rowptr,
                                               const int* __restrict__ col,
                                               const float* __restrict__ attl,
                                               const float* __restrict__ attr,
                                               const float* __restrict__ b2,
                                               float* __restrict__ out) {
    int wid = (blockIdx.x * blockDim.x + threadIdx.x) >> 6;  // node
    int lane = threadIdx.x & 63;
    if (wid >= N_NODES) return;
    const float2* h2v = (const float2*)h2;
    float2 xi = h2v[(size_t)wid * 64 + lane];
    float2 al = ((const float2*)attl)[lane];
    float2 ar = ((const float2*)attr)[lane];
    float ard = xi.x * ar.x + xi.y * ar.y;
    ard += __shfl_xor(ard, 1); ard += __shfl_xor(ard, 2); ard += __shfl_xor(ard, 4);
    int beg = rowptr[wid], end = rowptr[wid + 1];

    float m = -INFINITY, lsum = 0.f;
    float2 acc = make_float2(0.f, 0.f);
    int e = beg;
    int s = col[e];
    float2 xj = h2v[(size_t)s * 64 + lane];
    while (true) {
        float2 xjc = xj;
        int en = e + 1;
        if (en < end) {
            int s2 = col[en];
            xj = h2v[(size_t)s2 * 64 + lane];
        }
        float dot = xi.x * xjc.x + xi.y * xjc.y;
        float ald = xjc.x * al.x + xjc.y * al.y;
        dot += __shfl_xor(dot, 1); ald += __shfl_xor(ald, 1);
        dot += __shfl_xor(dot, 2); ald += __shfl_xor(ald, 2);
        dot += __shfl_xor(dot, 4); ald += __shfl_xor(ald, 4);
        float a = (ald + ard) * (1.f / (1.f + __expf(-dot)));
        a = a > 0.f ? a : NEG_SLOPE * a;
        float mn = fmaxf(m, a);
        float so = __expf(m - mn);
        float p = __expf(a - mn);
        lsum = lsum * so + p;
        acc.x = acc.x * so + p * xjc.x;
        acc.y = acc.y * so + p * xjc.y;
        m = mn;
        e = en;
        if (e >= end) break;
    }
    float ox = acc.x / lsum;
    float oy = acc.y / lsum;
    // mean over heads: lane l holds channels (head=l>>3, c=2*(l&7), +1);
    // sum over lanes with equal (l&7) => xor 8,16,32
    ox += __shfl_xor(ox, 8); oy += __shfl_xor(oy, 8);
    ox += __shfl_xor(ox, 16); oy += __shfl_xor(oy, 16);
    ox += __shfl_xor(ox, 32); oy += __shfl_xor(oy, 32);
    int c2 = (lane & 7) * 2;
    float vx = ox * 0.125f + b2[c2];
    float vy = oy * 0.125f + b2[c2 + 1];
    // log_softmax across 16 channels held by the 8-lane group (2 per lane)
    float mx = fmaxf(vx, vy);
    mx = fmaxf(mx, __shfl_xor(mx, 1));
    mx = fmaxf(mx, __shfl_xor(mx, 2));
    mx = fmaxf(mx, __shfl_xor(mx, 4));
    float se = __expf(vx - mx) + __expf(vy - mx);
    se += __shfl_xor(se, 1); se += __shfl_xor(se, 2); se += __shfl_xor(se, 4);
    float ls = __logf(se);
    if (lane < 8)
        ((float2*)out)[(size_t)wid * 8 + lane] = make_float2(vx - mx - ls, vy - mx - ls);
}

// ---------------- host ----------------
extern "C" void kernel_launch(void* const* d_in, const int* in_sizes, int n_in,
                              void* d_out, int out_size, void* d_ws, size_t ws_size,
                              hipStream_t stream) {
    const float* x     = (const float*)d_in[0];
    const int*   ei    = (const int*)d_in[1];
    const float* W1    = (const float*)d_in[2];
    const float* attl1 = (const float*)d_in[3];
    const float* attr1 = (const float*)d_in[4];
    const float* b1    = (const float*)d_in[5];
    const float* W2    = (const float*)d_in[6];
    const float* attl2 = (const float*)d_in[7];
    const float* attr2 = (const float*)d_in[8];
    const float* b2    = (const float*)d_in[9];
    float* out = (float*)d_out;

    char* ws = (char*)d_ws;
    size_t off = 0;
    auto alloc = [&](size_t bytes) {
        size_t o = off;
        off += (bytes + 255) & ~(size_t)255;
        return o;
    };
    size_t o_flag   = alloc(4);
    size_t o_counts = alloc((size_t)N_NODES * 4);
    size_t o_fill   = alloc((size_t)N_NODES * 4);
    size_t o_rowptr = alloc((size_t)(N_NODES + 1) * 4);
    size_t o_bsums  = alloc(1024 * 4);
    size_t o_col    = alloc((size_t)EPRIME * 4);
    size_t o_h1     = alloc((size_t)N_NODES * 64 * 4);
    size_t o_hout   = alloc((size_t)N_NODES * 64 * 4);
    size_t o_h2     = alloc((size_t)N_NODES * 128 * 4);

    unsigned* flag = (unsigned*)(ws + o_flag);
    int* counts = (int*)(ws + o_counts);
    int* fill   = (int*)(ws + o_fill);
    int* rowptr = (int*)(ws + o_rowptr);
    int* bsums  = (int*)(ws + o_bsums);
    int* col    = (int*)(ws + o_col);
    float* h1   = (float*)(ws + o_h1);
    float* hout = (float*)(ws + o_hout);
    float* h2   = (float*)(ws + o_h2);

    int nscan = (N_NODES + 1 + 1023) / 1024;  // 99

    hipLaunchKernelGGL(detect_k, dim3(1), dim3(256), 0, stream, (const unsigned*)ei, flag);
    hipLaunchKernelGGL(init_k, dim3((N_NODES + 255) / 256), dim3(256), 0, stream, counts, fill);
    hipLaunchKernelGGL(count_k, dim3((N_EDGES + 255) / 256), dim3(256), 0, stream, ei, flag, counts);
    hipLaunchKernelGGL(scan1_k, dim3(nscan), dim3(256), 0, stream, counts, rowptr, bsums);
    hipLaunchKernelGGL(scan2_k, dim3(1), dim3(64), 0, stream, bsums, nscan);
    hipLaunchKernelGGL(scan3_k, dim3(nscan), dim3(256), 0, stream, rowptr, bsums);
    hipLaunchKernelGGL(scatter_k, dim3((EPRIME + 255) / 256), dim3(256), 0, stream,
                       ei, flag, rowptr, fill, col);
    hipLaunchKernelGGL(gemm1_k, dim3((N_NODES + 31) / 32), dim3(256), 0, stream, x, W1, h1);
    hipLaunchKernelGGL(attn1_k, dim3((N_NODES + 3) / 4), dim3(256), 0, stream,
                       h1, rowptr, col, attl1, attr1, b1, hout);
    hipLaunchKernelGGL(gemm2_k, dim3((N_NODES + 31) / 32), dim3(256), 0, stream, hout, W2, h2);
    hipLaunchKernelGGL(attn2_k, dim3((N_NODES + 3) / 4), dim3(256), 0, stream,
                       h2, rowptr, col, attl2, attr2, b2, out);
}

// Round 2
// 806.824 us; speedup vs baseline: 1.0646x; 1.0646x over previous
//
#include <hip/hip_runtime.h>
#include <math.h>

#define N_NODES 100000
#define N_EDGES 1600000
#define EPRIME  (N_EDGES + N_NODES)
#define NEG_SLOPE 0.2f

// ---------------- edge dtype detect (int64 vs int32) ----------------
__global__ __launch_bounds__(256) void detect_k(const unsigned* __restrict__ w,
                                                unsigned* __restrict__ flag) {
    __shared__ int any;
    if (threadIdx.x == 0) any = 0;
    __syncthreads();
    int nz = 0;
    for (int i = threadIdx.x; i < 1024; i += 256)
        if (w[2 * i + 1] != 0u) nz = 1;
    if (nz) atomicOr(&any, 1);
    __syncthreads();
    if (threadIdx.x == 0) flag[0] = any ? 0u : 1u;  // 1 => int64
}

// ---------------- CSR build ----------------
__global__ __launch_bounds__(256) void init_k(int* __restrict__ counts,
                                              int* __restrict__ fill) {
    int n = blockIdx.x * blockDim.x + threadIdx.x;
    if (n < N_NODES) { counts[n] = 1; fill[n] = 0; }  // 1 = self loop
}

__global__ __launch_bounds__(256) void count_k(const int* __restrict__ ei,
                                               const unsigned* __restrict__ flag,
                                               int* __restrict__ counts) {
    int e = blockIdx.x * blockDim.x + threadIdx.x;
    if (e >= N_EDGES) return;
    int d = flag[0] ? ei[2 * (N_EDGES + e)] : ei[N_EDGES + e];
    atomicAdd(&counts[d], 1);
}

// exclusive scan of counts[0..N-1] -> rowptr[0..N], 1024 elems/block
__global__ __launch_bounds__(256) void scan1_k(const int* __restrict__ counts,
                                               int* __restrict__ rowptr,
                                               int* __restrict__ bsums) {
    __shared__ int s[256];
    int t = threadIdx.x;
    int base = blockIdx.x * 1024 + t * 4;
    int v[4];
#pragma unroll
    for (int j = 0; j < 4; ++j)
        v[j] = (base + j < N_NODES) ? counts[base + j] : 0;
    int tsum = v[0] + v[1] + v[2] + v[3];
    s[t] = tsum;
    __syncthreads();
    for (int off = 1; off < 256; off <<= 1) {
        int x = (t >= off) ? s[t - off] : 0;
        __syncthreads();
        s[t] += x;
        __syncthreads();
    }
    if (t == 255) bsums[blockIdx.x] = s[255];
    int run = s[t] - tsum;  // exclusive prefix for this thread (block-local)
#pragma unroll
    for (int j = 0; j < 4; ++j) {
        if (base + j <= N_NODES) rowptr[base + j] = run;
        run += v[j];
    }
}

__global__ void scan2_k(int* __restrict__ bsums, int nb) {
    if (threadIdx.x == 0 && blockIdx.x == 0) {
        int run = 0;
        for (int i = 0; i < nb; ++i) { int c = bsums[i]; bsums[i] = run; run += c; }
    }
}

__global__ __launch_bounds__(256) void scan3_k(int* __restrict__ rowptr,
                                               const int* __restrict__ bsums) {
    int t = threadIdx.x;
    int base = blockIdx.x * 1024 + t * 4;
    int add = bsums[blockIdx.x];
#pragma unroll
    for (int j = 0; j < 4; ++j)
        if (base + j <= N_NODES) rowptr[base + j] += add;
}

__global__ __launch_bounds__(256) void scatter_k(const int* __restrict__ ei,
                                                 const unsigned* __restrict__ flag,
                                                 const int* __restrict__ rowptr,
                                                 int* __restrict__ fill,
                                                 int* __restrict__ col) {
    int t = blockIdx.x * blockDim.x + threadIdx.x;
    if (t >= EPRIME) return;
    int s, d;
    if (t < N_EDGES) {
        if (flag[0]) { s = ei[2 * t]; d = ei[2 * (N_EDGES + t)]; }
        else         { s = ei[t];     d = ei[N_EDGES + t]; }
    } else {
        s = d = t - N_EDGES;
    }
    int pos = rowptr[d] + atomicAdd(&fill[d], 1);
    col[pos] = s;
}

// ---------------- GEMM1: h1 = x @ W1  (N x 512) @ (512 x 64) ----------------
// v2: 32 KB LDS (two K=256 chunks) for ~5 blocks/CU occupancy; 8-deep K-unroll
// with explicit W1 register prefetch to cover L2 latency.
__global__ __launch_bounds__(256) void gemm1_k(const float* __restrict__ x,
                                               const float* __restrict__ W1,
                                               float* __restrict__ h1) {
    __shared__ float xs[32 * 256];  // 32 KB
    int t = threadIdx.x;
    int row0 = blockIdx.x * 32;
    int w = t >> 6, lane = t & 63;
    int r0 = w * 8;
    float acc[8] = {0.f, 0.f, 0.f, 0.f, 0.f, 0.f, 0.f, 0.f};

    for (int kh = 0; kh < 2; ++kh) {
        __syncthreads();  // waves done reading previous chunk
        // stage 32 rows x 256 floats = 2048 float4; 8 per thread, coalesced
        for (int i = t; i < 32 * 64; i += 256) {
            int r = i >> 6, q = i & 63;
            int gr = row0 + r;
            float4 v = make_float4(0.f, 0.f, 0.f, 0.f);
            if (gr < N_NODES) v = ((const float4*)x)[(size_t)gr * 128 + kh * 64 + q];
            ((float4*)xs)[r * 64 + q] = v;
        }
        __syncthreads();

        const float* W1h = W1 + (size_t)(kh * 256) * 64 + lane;
        float wreg[8];
#pragma unroll
        for (int j = 0; j < 8; ++j) wreg[j] = W1h[j * 64];
        for (int kb = 0; kb < 32; ++kb) {
            float wn[8];
            if (kb < 31) {
#pragma unroll
                for (int j = 0; j < 8; ++j) wn[j] = W1h[(kb * 8 + 8 + j) * 64];
            } else {
#pragma unroll
                for (int j = 0; j < 8; ++j) wn[j] = 0.f;
            }
#pragma unroll
            for (int r = 0; r < 8; ++r) {
                float4 xa = ((const float4*)xs)[(r0 + r) * 64 + kb * 2];
                float4 xb = ((const float4*)xs)[(r0 + r) * 64 + kb * 2 + 1];
                acc[r] += xa.x * wreg[0] + xa.y * wreg[1] + xa.z * wreg[2] + xa.w * wreg[3]
                        + xb.x * wreg[4] + xb.y * wreg[5] + xb.z * wreg[6] + xb.w * wreg[7];
            }
#pragma unroll
            for (int j = 0; j < 8; ++j) wreg[j] = wn[j];
        }
    }
#pragma unroll
    for (int r = 0; r < 8; ++r) {
        int gr = row0 + r0 + r;
        if (gr < N_NODES) h1[(size_t)gr * 64 + lane] = acc[r];
    }
}

// ---------------- attn1: one wave per node, lane = channel (64ch) ----------------
__global__ __launch_bounds__(256) void attn1_k(const float* __restrict__ h1,
                                               const int* __restrict__ rowptr,
                                               const int* __restrict__ col,
                                               const float* __restrict__ attl,
                                               const float* __restrict__ attr,
                                               const float* __restrict__ b1,
                                               float* __restrict__ hout) {
    int wid = (blockIdx.x * blockDim.x + threadIdx.x) >> 6;  // node
    int lane = threadIdx.x & 63;
    if (wid >= N_NODES) return;
    float xi = h1[(size_t)wid * 64 + lane];
    float al = attl[lane];
    float ar = attr[lane];
    float ard = xi * ar;
    ard += __shfl_xor(ard, 1); ard += __shfl_xor(ard, 2); ard += __shfl_xor(ard, 4);
    int beg = rowptr[wid], end = rowptr[wid + 1];

    float m = -INFINITY, lsum = 0.f, acc = 0.f;
    int e = beg;
    int s = col[e];
    float xj = h1[(size_t)s * 64 + lane];
    while (true) {
        float xjc = xj;
        int en = e + 1;
        if (en < end) {
            int s2 = col[en];
            xj = h1[(size_t)s2 * 64 + lane];
        }
        float dot = xi * xjc;
        float ald = xjc * al;
        dot += __shfl_xor(dot, 1); ald += __shfl_xor(ald, 1);
        dot += __shfl_xor(dot, 2); ald += __shfl_xor(ald, 2);
        dot += __shfl_xor(dot, 4); ald += __shfl_xor(ald, 4);
        float a = (ald + ard) * (1.f / (1.f + __expf(-dot)));
        a = a > 0.f ? a : NEG_SLOPE * a;
        float mn = fmaxf(m, a);
        float so = __expf(m - mn);
        float p = __expf(a - mn);
        lsum = lsum * so + p;
        acc = acc * so + p * xjc;
        m = mn;
        e = en;
        if (e >= end) break;
    }
    float o = acc / lsum + b1[lane];
    o = o > 0.f ? o : (__expf(o) - 1.f);  // ELU
    hout[(size_t)wid * 64 + lane] = o;
}

// ---------------- GEMM2: h2 = hout @ W2  (N x 64) @ (64 x 128) ----------------
__global__ __launch_bounds__(256) void gemm2_k(const float* __restrict__ h,
                                               const float* __restrict__ W2,
                                               float* __restrict__ h2) {
    __shared__ float xs[32 * 64];
    int t = threadIdx.x;
    int row0 = blockIdx.x * 32;
    for (int i = t; i < 32 * 16; i += 256) {
        int r = i >> 4, q = i & 15;
        int gr = row0 + r;
        float4 v = make_float4(0.f, 0.f, 0.f, 0.f);
        if (gr < N_NODES) v = ((const float4*)h)[(size_t)gr * 16 + q];
        ((float4*)xs)[r * 16 + q] = v;
    }
    __syncthreads();
    int w = t >> 6, lane = t & 63;
    int r0 = w * 8;
    float2 acc[8];
#pragma unroll
    for (int r = 0; r < 8; ++r) acc[r] = make_float2(0.f, 0.f);
    for (int k = 0; k < 64; ++k) {
        float2 wv = ((const float2*)W2)[k * 64 + lane];
#pragma unroll
        for (int r = 0; r < 8; ++r) {
            float xv = xs[(r0 + r) * 64 + k];
            acc[r].x += xv * wv.x;
            acc[r].y += xv * wv.y;
        }
    }
#pragma unroll
    for (int r = 0; r < 8; ++r) {
        int gr = row0 + r0 + r;
        if (gr < N_NODES) ((float2*)h2)[(size_t)gr * 64 + lane] = acc[r];
    }
}

// ---------------- attn2: one wave per node, 2 channels/lane (128ch) ----------------
// fused: online softmax agg + head mean + bias + log_softmax
__global__ __launch_bounds__(256) void attn2_k(const float* __restrict__ h2,
                                               const int* __restrict__ rowptr,
                                               const int* __restrict__ col,
                                               const float* __restrict__ attl,
                                               const float* __restrict__ attr,
                                               const float* __restrict__ b2,
                                               float* __restrict__ out) {
    int wid = (blockIdx.x * blockDim.x + threadIdx.x) >> 6;  // node
    int lane = threadIdx.x & 63;
    if (wid >= N_NODES) return;
    const float2* h2v = (const float2*)h2;
    float2 xi = h2v[(size_t)wid * 64 + lane];
    float2 al = ((const float2*)attl)[lane];
    float2 ar = ((const float2*)attr)[lane];
    float ard = xi.x * ar.x + xi.y * ar.y;
    ard += __shfl_xor(ard, 1); ard += __shfl_xor(ard, 2); ard += __shfl_xor(ard, 4);
    int beg = rowptr[wid], end = rowptr[wid + 1];

    float m = -INFINITY, lsum = 0.f;
    float2 acc = make_float2(0.f, 0.f);
    int e = beg;
    int s = col[e];
    float2 xj = h2v[(size_t)s * 64 + lane];
    while (true) {
        float2 xjc = xj;
        int en = e + 1;
        if (en < end) {
            int s2 = col[en];
            xj = h2v[(size_t)s2 * 64 + lane];
        }
        float dot = xi.x * xjc.x + xi.y * xjc.y;
        float ald = xjc.x * al.x + xjc.y * al.y;
        dot += __shfl_xor(dot, 1); ald += __shfl_xor(ald, 1);
        dot += __shfl_xor(dot, 2); ald += __shfl_xor(ald, 2);
        dot += __shfl_xor(dot, 4); ald += __shfl_xor(ald, 4);
        float a = (ald + ard) * (1.f / (1.f + __expf(-dot)));
        a = a > 0.f ? a : NEG_SLOPE * a;
        float mn = fmaxf(m, a);
        float so = __expf(m - mn);
        float p = __expf(a - mn);
        lsum = lsum * so + p;
        acc.x = acc.x * so + p * xjc.x;
        acc.y = acc.y * so + p * xjc.y;
        m = mn;
        e = en;
        if (e >= end) break;
    }
    float ox = acc.x / lsum;
    float oy = acc.y / lsum;
    // mean over heads: lane l holds channels (head=l>>3, c=2*(l&7), +1);
    // sum over lanes with equal (l&7) => xor 8,16,32
    ox += __shfl_xor(ox, 8); oy += __shfl_xor(oy, 8);
    ox += __shfl_xor(ox, 16); oy += __shfl_xor(oy, 16);
    ox += __shfl_xor(ox, 32); oy += __shfl_xor(oy, 32);
    int c2 = (lane & 7) * 2;
    float vx = ox * 0.125f + b2[c2];
    float vy = oy * 0.125f + b2[c2 + 1];
    // log_softmax across 16 channels held by the 8-lane group (2 per lane)
    float mx = fmaxf(vx, vy);
    mx = fmaxf(mx, __shfl_xor(mx, 1));
    mx = fmaxf(mx, __shfl_xor(mx, 2));
    mx = fmaxf(mx, __shfl_xor(mx, 4));
    float se = __expf(vx - mx) + __expf(vy - mx);
    se += __shfl_xor(se, 1); se += __shfl_xor(se, 2); se += __shfl_xor(se, 4);
    float ls = __logf(se);
    if (lane < 8)
        ((float2*)out)[(size_t)wid * 8 + lane] = make_float2(vx - mx - ls, vy - mx - ls);
}

// ---------------- host ----------------
extern "C" void kernel_launch(void* const* d_in, const int* in_sizes, int n_in,
                              void* d_out, int out_size, void* d_ws, size_t ws_size,
                              hipStream_t stream) {
    const float* x     = (const float*)d_in[0];
    const int*   ei    = (const int*)d_in[1];
    const float* W1    = (const float*)d_in[2];
    const float* attl1 = (const float*)d_in[3];
    const float* attr1 = (const float*)d_in[4];
    const float* b1    = (const float*)d_in[5];
    const float* W2    = (const float*)d_in[6];
    const float* attl2 = (const float*)d_in[7];
    const float* attr2 = (const float*)d_in[8];
    const float* b2    = (const float*)d_in[9];
    float* out = (float*)d_out;

    char* ws = (char*)d_ws;
    size_t off = 0;
    auto alloc = [&](size_t bytes) {
        size_t o = off;
        off += (bytes + 255) & ~(size_t)255;
        return o;
    };
    size_t o_flag   = alloc(4);
    size_t o_counts = alloc((size_t)N_NODES * 4);
    size_t o_fill   = alloc((size_t)N_NODES * 4);
    size_t o_rowptr = alloc((size_t)(N_NODES + 1) * 4);
    size_t o_bsums  = alloc(1024 * 4);
    size_t o_col    = alloc((size_t)EPRIME * 4);
    size_t o_h1     = alloc((size_t)N_NODES * 64 * 4);
    size_t o_hout   = alloc((size_t)N_NODES * 64 * 4);
    size_t o_h2     = alloc((size_t)N_NODES * 128 * 4);

    unsigned* flag = (unsigned*)(ws + o_flag);
    int* counts = (int*)(ws + o_counts);
    int* fill   = (int*)(ws + o_fill);
    int* rowptr = (int*)(ws + o_rowptr);
    int* bsums  = (int*)(ws + o_bsums);
    int* col    = (int*)(ws + o_col);
    float* h1   = (float*)(ws + o_h1);
    float* hout = (float*)(ws + o_hout);
    float* h2   = (float*)(ws + o_h2);

    int nscan = (N_NODES + 1 + 1023) / 1024;  // 99

    hipLaunchKernelGGL(detect_k, dim3(1), dim3(256), 0, stream, (const unsigned*)ei, flag);
    hipLaunchKernelGGL(init_k, dim3((N_NODES + 255) / 256), dim3(256), 0, stream, counts, fill);
    hipLaunchKernelGGL(count_k, dim3((N_EDGES + 255) / 256), dim3(256), 0, stream, ei, flag, counts);
    hipLaunchKernelGGL(scan1_k, dim3(nscan), dim3(256), 0, stream, counts, rowptr, bsums);
    hipLaunchKernelGGL(scan2_k, dim3(1), dim3(64), 0, stream, bsums, nscan);
    hipLaunchKernelGGL(scan3_k, dim3(nscan), dim3(256), 0, stream, rowptr, bsums);
    hipLaunchKernelGGL(scatter_k, dim3((EPRIME + 255) / 256), dim3(256), 0, stream,
                       ei, flag, rowptr, fill, col);
    hipLaunchKernelGGL(gemm1_k, dim3((N_NODES + 31) / 32), dim3(256), 0, stream, x, W1, h1);
    hipLaunchKernelGGL(attn1_k, dim3((N_NODES + 3) / 4), dim3(256), 0, stream,
                       h1, rowptr, col, attl1, attr1, b1, hout);
    hipLaunchKernelGGL(gemm2_k, dim3((N_NODES + 31) / 32), dim3(256), 0, stream, hout, W2, h2);
    hipLaunchKernelGGL(attn2_k, dim3((N_NODES + 3) / 4), dim3(256), 0, stream,
                       h2, rowptr, col, attl2, attr2, b2, out);
}